// Round 19
// baseline (128.374 us; speedup 1.0000x reference)
//
#include <hip/hip_runtime.h>
#include <hip/hip_bf16.h>
#include <stdint.h>

typedef __bf16 bf16x8 __attribute__((ext_vector_type(8)));
typedef float  f32x4  __attribute__((ext_vector_type(4)));

typedef __attribute__((address_space(1))) void gas1_t;
typedef __attribute__((address_space(3))) void as3_t;

__device__ __forceinline__ void gload_lds16(const void* g, void* l) {
  // width=16 global->LDS DMA; LDS dest is wave-uniform base + lane*16
  __builtin_amdgcn_global_load_lds((gas1_t*)g, (as3_t*)l, 16, 0, 0);
}

__device__ __forceinline__ f32x4 zero4() { f32x4 z = {0.f, 0.f, 0.f, 0.f}; return z; }

__device__ __forceinline__ unsigned pack_bf16x2(float a, float b) {
  __bf16 ha = (__bf16)a, hb = (__bf16)b;
  unsigned short ua = *(unsigned short*)&ha, ub = *(unsigned short*)&hb;
  return (unsigned)ua | ((unsigned)ub << 16);
}

// native 2^x: single v_exp_f32 (ISA section 3: v_exp_f32 computes 2^S0)
__device__ __forceinline__ float fast_exp2(float x) {
  float r;
  asm("v_exp_f32 %0, %1" : "=v"(r) : "v"(x));
  return r;
}

// ---------------- float -> bf16 cast, 8 elems/thread ----------------
__global__ void cvt_f32_to_bf16(const float* __restrict__ in, __bf16* __restrict__ out, int n) {
  int i = (blockIdx.x * 256 + threadIdx.x) * 8;
  if (i >= n) return;
  const f32x4 v0 = *(const f32x4*)(in + i);
  const f32x4 v1 = *(const f32x4*)(in + i + 4);
  bf16x8 o;
#pragma unroll
  for (int j = 0; j < 4; ++j) { o[j] = (__bf16)v0[j]; o[j + 4] = (__bf16)v1[j]; }
  *(bf16x8*)(out + i) = o;
}

// ---------------- transpose + cast: W[K][N] f32 -> WT[N][K] bf16 ----------------
__global__ void transpose_cast(const float* __restrict__ W, __bf16* __restrict__ WT,
                               int K, int N) {
  __shared__ float tile[32][33];
  const int n0 = blockIdx.x * 32, k0 = blockIdx.y * 32;
  const int tx = threadIdx.x, ty = threadIdx.y;
  for (int i = ty; i < 32; i += 8) tile[i][tx] = W[(size_t)(k0 + i) * N + n0 + tx];
  __syncthreads();
  for (int i = ty; i < 32; i += 8) WT[(size_t)(n0 + i) * K + k0 + tx] = (__bf16)tile[tx][i];
}

// ---------------- merged prep (big_ws path): cvt(x) + transpose(Wqkv) + transpose(Wout) ----
// grid 6144 x 256: [0,2048) cvt 8/thread; [2048,5120) Wqkv tiles; [5120,6144) Wout tiles.
__global__ __launch_bounds__(256) void prep_all(const float* __restrict__ x, __bf16* __restrict__ xb,
                                                const float* __restrict__ Wqkv, __bf16* __restrict__ wqkvT,
                                                const float* __restrict__ Wout, __bf16* __restrict__ woutT) {
  const int bid = blockIdx.x;
  if (bid < 2048) {
    const int i = (bid * 256 + threadIdx.x) * 8;
    const f32x4 v0 = *(const f32x4*)(x + i);
    const f32x4 v1 = *(const f32x4*)(x + i + 4);
    bf16x8 o;
#pragma unroll
    for (int j = 0; j < 4; ++j) { o[j] = (__bf16)v0[j]; o[j + 4] = (__bf16)v1[j]; }
    *(bf16x8*)(xb + i) = o;
    return;
  }
  __shared__ float tile[32][33];
  const int tx = threadIdx.x & 31, ty = threadIdx.x >> 5;
  const float* W; __bf16* WT; int N, n0, k0;
  if (bid < 5120) {
    const int l = bid - 2048;                      // 3072 tiles: [96 n-tiles][32 k-tiles]
    W = Wqkv; WT = wqkvT; N = 3072;
    n0 = (l % 96) * 32; k0 = (l / 96) * 32;
  } else {
    const int l = bid - 5120;                      // 1024 tiles: [32][32]
    W = Wout; WT = woutT; N = 1024;
    n0 = (l & 31) * 32; k0 = (l >> 5) * 32;
  }
  for (int i = ty; i < 32; i += 8) tile[i][tx] = W[(size_t)(k0 + i) * N + n0 + tx];
  __syncthreads();
  for (int i = ty; i < 32; i += 8) WT[(size_t)(n0 + i) * 1024 + k0 + tx] = (__bf16)tile[tx][i];
}

// ---------------- GEMM: C[M][N] = A[M][K] @ BT[N][K]^T + bias ----------------
// SCALE_Q: multiply columns < 1024 by 0.125*log2(e). BN64: 128x64 tile (waves 2x2,
// each 64x32) -> 2x the blocks (occupancy fix for tiny grids ONLY, e.g. GEMM2).
template <int OUT_BF16, int A_F32, int SCALE_Q, int BN64>
__global__ __launch_bounds__(256) void gemm_bt(const void* __restrict__ Ap,
                                               const __bf16* __restrict__ BT,
                                               const float* __restrict__ bias,
                                               void* __restrict__ Cout,
                                               int M, int N, int K) {
  __shared__ __bf16 As[2][4096];                 // [128][32] bf16, linear
  __shared__ __bf16 Bs[2][BN64 ? 2048 : 4096];   // [BN][32] bf16, linear
  const int tid = threadIdx.x;
  const int lane = tid & 63, w = tid >> 6;
  const int wr = w >> 1, wc = w & 1;
  const int lgrp = lane >> 4, lcol = lane & 15;
  const int BN = BN64 ? 64 : 128;
  const int WCS = BN64 ? 32 : 64;                // wave column span
  const int NN = BN64 ? 2 : 4;                   // 16-col subtiles per wave
  const int m0 = blockIdx.y * 128, n0 = blockIdx.x * BN;

  f32x4 acc[4][BN64 ? 2 : 4];
#pragma unroll
  for (int m = 0; m < 4; ++m)
#pragma unroll
    for (int n = 0; n < NN; ++n) acc[m][n] = zero4();

  const int nk = K >> 5;

  auto stageB = [&](int buf, int k0) {
    if (BN64) {
      const int c = tid;                          // 256 chunks = 64 rows x 4
      const int row = c >> 2, kc = (c & 3) * 8;
      const int ldsoff = (w * 64) * 16;           // wave-uniform
      gload_lds16(BT + (size_t)(n0 + row) * K + k0 + kc, (char*)&Bs[buf][0] + ldsoff);
    } else {
#pragma unroll
      for (int q = 0; q < 2; ++q) {
        const int c = q * 256 + w * 64 + lane;
        const int row = c >> 2, kc = (c & 3) * 8;
        const int ldsoff = (q * 256 + w * 64) * 16;
        gload_lds16(BT + (size_t)(n0 + row) * K + k0 + kc, (char*)&Bs[buf][0] + ldsoff);
      }
    }
  };
  auto stageA = [&](int buf, int k0) {
    if (A_F32) {
      const float* A = (const float*)Ap;
      const int c0 = tid * 2;
      const int row = c0 >> 2, kc = (c0 & 3) * 8;
      const float* src = A + (size_t)(m0 + row) * K + k0 + kc;
      const f32x4 v0 = *(const f32x4*)(src);
      const f32x4 v1 = *(const f32x4*)(src + 4);
      const f32x4 v2 = *(const f32x4*)(src + 8);
      const f32x4 v3 = *(const f32x4*)(src + 12);
      bf16x8 o0, o1;
#pragma unroll
      for (int j = 0; j < 4; ++j) {
        o0[j] = (__bf16)v0[j]; o0[j + 4] = (__bf16)v1[j];
        o1[j] = (__bf16)v2[j]; o1[j + 4] = (__bf16)v3[j];
      }
      *(bf16x8*)((char*)&As[buf][0] + c0 * 16) = o0;
      *(bf16x8*)((char*)&As[buf][0] + c0 * 16 + 16) = o1;
    } else {
      const __bf16* A = (const __bf16*)Ap;
#pragma unroll
      for (int q = 0; q < 2; ++q) {
        const int c = q * 256 + w * 64 + lane;
        const int row = c >> 2, kc = (c & 3) * 8;
        const int ldsoff = (q * 256 + w * 64) * 16;
        gload_lds16(A + (size_t)(m0 + row) * K + k0 + kc, (char*)&As[buf][0] + ldsoff);
      }
    }
  };

  stageA(0, 0);
  stageB(0, 0);
  __syncthreads();
  int cur = 0;
  for (int t = 0; t < nk; ++t) {
    if (t + 1 < nk) { stageA(cur ^ 1, (t + 1) * 32); stageB(cur ^ 1, (t + 1) * 32); }
    bf16x8 af[4], bfr[BN64 ? 2 : 4];
#pragma unroll
    for (int m = 0; m < 4; ++m)
      af[m] = *(const bf16x8*)&As[cur][(wr * 64 + m * 16 + lcol) * 32 + lgrp * 8];
#pragma unroll
    for (int n = 0; n < NN; ++n)
      bfr[n] = *(const bf16x8*)&Bs[cur][(wc * WCS + n * 16 + lcol) * 32 + lgrp * 8];
    __builtin_amdgcn_s_setprio(1);
#pragma unroll
    for (int m = 0; m < 4; ++m)
#pragma unroll
      for (int n = 0; n < NN; ++n)
        acc[m][n] = __builtin_amdgcn_mfma_f32_16x16x32_bf16(af[m], bfr[n], acc[m][n], 0, 0, 0);
    __builtin_amdgcn_s_setprio(0);
    __syncthreads();
    cur ^= 1;
  }

#pragma unroll
  for (int m = 0; m < 4; ++m) {
#pragma unroll
    for (int n = 0; n < NN; ++n) {
      const int col = n0 + wc * WCS + n * 16 + lcol;
      const float bv = bias[col];
#pragma unroll
      for (int r = 0; r < 4; ++r) {
        const int row = m0 + wr * 64 + m * 16 + lgrp * 4 + r;
        float v = acc[m][n][r] + bv;
        if (SCALE_Q && col < 1024) v *= 0.18033688011112042f;  // log2(e)/8
        if (OUT_BF16)
          ((__bf16*)Cout)[(size_t)row * N + col] = (__bf16)v;
        else
          ((float*)Cout)[(size_t)row * N + col] = v;
      }
    }
  }
}

// ---------------- fused causal flash attention (v12 = v11 + T1 XCD-affinity) ----
// Flat grid 512. Bijective remap: xcd = id&7 owns bh in [4*xcd, 4*xcd+4) -> each
// XCD's K/V working set = 4 x 512KB = 2MB < 4MB L2 (all K/V staging L2-hits after
// first touch). Block owns 128 q-rows (8 waves x 16), KV tile = 128 (two 64-halves).
// Swapped-operand MFMA (S^T / O^T), in-register softmax via native v_exp_f32,
// merged PV, T13 defer-max. Q pre-scaled by log2(e)/8 in GEMM1.
__global__ __launch_bounds__(512, 4) void attn_fused(const __bf16* __restrict__ qkv,
                                                     __bf16* __restrict__ attnb) {
  __shared__ __bf16 Kl[2][64][80];    // K halves [kv][d]
  __shared__ __bf16 Vt[2][64][80];    // V^T halves [d][kv], colblk ^= (kv>>3)&7
  __shared__ __bf16 Pl[8][16][144];   // per-wave P^T [q][kv 0..127], group ^= (q>>2)&3
  const int tid = threadIdx.x, lane = tid & 63, w = tid >> 6;
  const int lgrp = lane >> 4, lcol = lane & 15;
  // T1: id -> (xcd, k) -> (bh, xv); bijective (inverse: k = ((bh&3)<<4)|xv, id = (k<<3)|xcd)
  const int id = blockIdx.x;
  const int xcd = id & 7, kk = id >> 3;
  const int bh = (xcd << 2) | (kk >> 4);          // 4 bh per XCD
  const int xv = kk & 15;
  const int xp = (bh & 16) ? (15 - xv) : xv;      // pair balance preserved
  const int b = bh >> 4, h = bh & 15;
  const __bf16* base = qkv + (size_t)b * 2048 * 3072;

  const int qb = xp * 128;            // block q start
  const int rw = qb + w * 16;         // wave q start
  const int nkv = xp + 1;             // number of 128-kv rounds

  // staging: thread covers K/V rows krow and krow+64, cols d00..d00+7
  const int krow = tid >> 3;          // 0..63
  const int d00 = (tid & 7) * 8;
  const int vcol = ((((krow >> 3) ^ (tid & 7)) << 3) | (krow & 7));  // Vt swizzle
  const __bf16* kvp = base + 1024 + h * 64 + d00;

  // Q fragment (B-operand): col = q = lcol, k(d) = lgrp*8 + j (+32 per slice)
  const int q_l = rw + lcol;          // this lane's q-row
  const __bf16* qptr = base + (size_t)q_l * 3072 + h * 64;
  const bf16x8 qf0 = *(const bf16x8*)(qptr + lgrp * 8);
  const bf16x8 qf1 = *(const bf16x8*)(qptr + 32 + lgrp * 8);

  float m1 = -1e30f, l1 = 0.f;        // own-row softmax state (log2 domain)
  f32x4 acc_o[4];                     // O^T: row d = dsub*16 + 4*lgrp + r
#pragma unroll
  for (int d = 0; d < 4; ++d) acc_o[d] = zero4();

  // prefetch round 0 (2 K-vecs + 2 V-vecs per thread)
  bf16x8 kf0 = *(const bf16x8*)(kvp + (size_t)krow * 3072);
  bf16x8 vf0 = *(const bf16x8*)(kvp + (size_t)krow * 3072 + 1024);
  bf16x8 kf1 = *(const bf16x8*)(kvp + (size_t)(krow + 64) * 3072);
  bf16x8 vf1 = *(const bf16x8*)(kvp + (size_t)(krow + 64) * 3072 + 1024);

  for (int kvb = 0; kvb < nkv; ++kvb) {
    const int kv0 = kvb * 128;
    __syncthreads();  // previous round's LDS reads complete
    *(bf16x8*)&Kl[0][krow][d00] = kf0;
    *(bf16x8*)&Kl[1][krow][d00] = kf1;
#pragma unroll
    for (int j = 0; j < 8; ++j) {
      Vt[0][d00 + j][vcol] = vf0[j];
      Vt[1][d00 + j][vcol] = vf1[j];
    }
    __syncthreads();
    // issue next round's global loads (latency hides under compute below)
    if (kvb + 1 < nkv) {
      const __bf16* p = kvp + (size_t)(kv0 + 128 + krow) * 3072;
      kf0 = *(const bf16x8*)p;
      vf0 = *(const bf16x8*)(p + 1024);
      kf1 = *(const bf16x8*)(p + (size_t)64 * 3072);
      vf1 = *(const bf16x8*)(p + (size_t)64 * 3072 + 1024);
    }

    const bool diag = (kvb == xp);          // only final round needs masking
    const bool skip1 = diag && (w < 4);     // waves 0-3: upper kv-half fully masked

    // S^T = K @ Q : D col = q = lcol, row = kv = sub*16 + 4*lgrp + r
    f32x4 accs[8];
    __builtin_amdgcn_s_setprio(1);
#pragma unroll
    for (int sub = 0; sub < 4; ++sub) {
      accs[sub] = zero4();
#pragma unroll
      for (int s = 0; s < 2; ++s) {
        const bf16x8 kb = *(const bf16x8*)&Kl[0][sub * 16 + lcol][s * 32 + lgrp * 8];
        accs[sub] = __builtin_amdgcn_mfma_f32_16x16x32_bf16(kb, s ? qf1 : qf0, accs[sub], 0, 0, 0);
      }
    }
    if (!skip1) {
#pragma unroll
      for (int sub = 0; sub < 4; ++sub) {
        accs[4 + sub] = zero4();
#pragma unroll
        for (int s = 0; s < 2; ++s) {
          const bf16x8 kb = *(const bf16x8*)&Kl[1][sub * 16 + lcol][s * 32 + lgrp * 8];
          accs[4 + sub] = __builtin_amdgcn_mfma_f32_16x16x32_bf16(kb, s ? qf1 : qf0, accs[4 + sub], 0, 0, 0);
        }
      }
    } else {
#pragma unroll
      for (int sub = 4; sub < 8; ++sub) accs[sub] = f32x4{-1e30f, -1e30f, -1e30f, -1e30f};
    }
    __builtin_amdgcn_s_setprio(0);

    // causal mask (diagonal round only); Q already carries scale
    if (diag) {
#pragma unroll
      for (int sub = 0; sub < 8; ++sub) {
        const int kvg = kv0 + sub * 16 + lgrp * 4;
#pragma unroll
        for (int r = 0; r < 4; ++r)
          if (kvg + r > q_l) accs[sub][r] = -1e30f;
      }
    }

    // in-register row max (tree) + 2 shfl across the 4 lanes sharing this row
    float mx[8];
#pragma unroll
    for (int sub = 0; sub < 8; ++sub)
      mx[sub] = fmaxf(fmaxf(accs[sub][0], accs[sub][1]), fmaxf(accs[sub][2], accs[sub][3]));
    float rm = fmaxf(fmaxf(fmaxf(mx[0], mx[1]), fmaxf(mx[2], mx[3])),
                     fmaxf(fmaxf(mx[4], mx[5]), fmaxf(mx[6], mx[7])));
    rm = fmaxf(rm, __shfl_xor(rm, 16));
    rm = fmaxf(rm, __shfl_xor(rm, 32));

    // T13 defer-max: only rescale when the new tile max exceeds m1 by > 8
    if (!__all(rm - m1 <= 8.0f)) {
      const float nm = fmaxf(m1, rm);
      const float sf = fast_exp2(m1 - nm);
      m1 = nm;
      l1 *= sf;
#pragma unroll
      for (int d = 0; d < 4; ++d)
#pragma unroll
        for (int r = 0; r < 4; ++r) acc_o[d][r] *= sf;
    }

    // exp2 in place (native v_exp_f32) + row sum (tree) + 2 shfl
    float ps[8];
#pragma unroll
    for (int sub = 0; sub < 8; ++sub) {
#pragma unroll
      for (int r = 0; r < 4; ++r) accs[sub][r] = fast_exp2(accs[sub][r] - m1);
      ps[sub] = (accs[sub][0] + accs[sub][1]) + (accs[sub][2] + accs[sub][3]);
    }
    float rs = ((ps[0] + ps[1]) + (ps[2] + ps[3])) + ((ps[4] + ps[5]) + (ps[6] + ps[7]));
    rs += __shfl_xor(rs, 16);
    rs += __shfl_xor(rs, 32);
    l1 += rs;

    // ---- merged PV: store P for BOTH halves, one waitcnt, one 16-MFMA run ----
#pragma unroll
    for (int sub = 0; sub < 4; ++sub) {
      uint2 pk;
      pk.x = pack_bf16x2(accs[sub][0], accs[sub][1]);
      pk.y = pack_bf16x2(accs[sub][2], accs[sub][3]);
      const int eoff = ((((sub * 2 + (lgrp >> 1)) ^ ((lcol >> 2) & 3)) << 3) | ((lgrp & 1) << 2));
      *(uint2*)&Pl[w][lcol][eoff] = pk;
    }
    if (!skip1) {
#pragma unroll
      for (int sub = 4; sub < 8; ++sub) {
        uint2 pk;
        pk.x = pack_bf16x2(accs[sub][0], accs[sub][1]);
        pk.y = pack_bf16x2(accs[sub][2], accs[sub][3]);
        const int eoff = ((((sub * 2 + (lgrp >> 1)) ^ ((lcol >> 2) & 3)) << 3) | ((lgrp & 1) << 2));
        *(uint2*)&Pl[w][lcol][eoff] = pk;
      }
    }
    asm volatile("s_waitcnt lgkmcnt(0)" ::: "memory");
    __builtin_amdgcn_sched_barrier(0);  // rule 18
    __builtin_amdgcn_s_setprio(1);
#pragma unroll
    for (int s = 0; s < 2; ++s) {
      const bf16x8 pf = *(const bf16x8*)&Pl[w][lcol][((4 * s + lgrp) ^ ((lcol >> 2) & 3)) * 8];
#pragma unroll
      for (int d = 0; d < 4; ++d) {
        const bf16x8 vfr = *(const bf16x8*)&Vt[0][d * 16 + lcol][((4 * s + lgrp) ^ ((2 * d + (lcol >> 3)) & 7)) * 8];
        acc_o[d] = __builtin_amdgcn_mfma_f32_16x16x32_bf16(vfr, pf, acc_o[d], 0, 0, 0);
      }
    }
    if (!skip1) {
#pragma unroll
      for (int s = 2; s < 4; ++s) {
        const bf16x8 pf = *(const bf16x8*)&Pl[w][lcol][((4 * s + lgrp) ^ ((lcol >> 2) & 3)) * 8];
#pragma unroll
        for (int d = 0; d < 4; ++d) {
          const bf16x8 vfr = *(const bf16x8*)&Vt[1][d * 16 + lcol][((4 * (s - 2) + lgrp) ^ ((2 * d + (lcol >> 3)) & 7)) * 8];
          acc_o[d] = __builtin_amdgcn_mfma_f32_16x16x32_bf16(vfr, pf, acc_o[d], 0, 0, 0);
        }
      }
    }
    __builtin_amdgcn_s_setprio(0);
  }

  // epilogue: O^T -> bf16 [B*T][1024]; lane owns q-row q_l, d = dsub*16+4*lgrp+{0..3}
  const float inv_l = 1.0f / l1;
  __bf16* orow = attnb + (size_t)(b * 2048 + q_l) * 1024 + h * 64 + lgrp * 4;
#pragma unroll
  for (int d = 0; d < 4; ++d) {
    uint2 ov;
    ov.x = pack_bf16x2(acc_o[d][0] * inv_l, acc_o[d][1] * inv_l);
    ov.y = pack_bf16x2(acc_o[d][2] * inv_l, acc_o[d][3] * inv_l);
    *(uint2*)(orow + d * 16) = ov;
  }
}

extern "C" void kernel_launch(void* const* d_in, const int* in_sizes, int n_in,
                              void* d_out, int out_size, void* d_ws, size_t ws_size,
                              hipStream_t stream) {
  const float* x    = (const float*)d_in[0];
  const float* Wqkv = (const float*)d_in[1];
  const float* bqkv = (const float*)d_in[2];
  const float* Wout = (const float*)d_in[3];
  const float* bout = (const float*)d_in[4];
  float* out = (float*)d_out;

  // Workspace plan (big_ws, >= 40MB):
  //   [0,24M)   qkvb  (bf16 [4096][3072])  -- dead after attn
  //   [24,30M)  wqkvT (bf16 [3072][1024])
  //   [30,38M)  xb    (bf16 [4096][1024])
  //   [38,40M)  woutT (bf16 [1024][1024])  -- no alias (prep runs before GEMM1)
  //   [24,32M)  attnb (bf16 [4096][1024])  -- over dead wqkvT
  // small_ws fallback (32MB peak): woutT over dead qkvb.
  char* ws = (char*)d_ws;
  __bf16* qkvb  = (__bf16*)(ws);
  __bf16* wqkvT = (__bf16*)(ws + (24u << 20));
  __bf16* xb    = (__bf16*)(ws + (30u << 20));
  __bf16* attnb = (__bf16*)(ws + (24u << 20));

  const bool big_ws = ws_size >= ((size_t)40 << 20);

  if (big_ws) {
    __bf16* woutT = (__bf16*)(ws + (38u << 20));
    prep_all<<<dim3(2048 + 3072 + 1024), dim3(256), 0, stream>>>(x, xb, Wqkv, wqkvT, Wout, woutT);
    // QKV-proj: proven BN128 path (3 blocks/CU, highest compute density)
    gemm_bt<1, 0, 1, 0><<<dim3(3072 / 128, 4096 / 128), dim3(256), 0, stream>>>(
        (const void*)xb, wqkvT, bqkv, (void*)qkvb, 4096, 3072, 1024);
    attn_fused<<<dim3(512), dim3(512), 0, stream>>>(qkvb, attnb);
    // out-proj: BN64 (512 blocks = 2 blocks/CU fixes occupancy-1 drain exposure)
    gemm_bt<0, 0, 0, 1><<<dim3(1024 / 64, 4096 / 128), dim3(256), 0, stream>>>(
        (const void*)attnb, woutT, bout, (void*)out, 4096, 1024, 1024);
  } else {
    __bf16* woutT = (__bf16*)(ws);
    transpose_cast<<<dim3(3072 / 32, 1024 / 32), dim3(32, 8), 0, stream>>>(Wqkv, wqkvT, 1024, 3072);
    gemm_bt<1, 1, 1, 0><<<dim3(3072 / 128, 4096 / 128), dim3(256), 0, stream>>>(
        (const void*)x, wqkvT, bqkv, (void*)qkvb, 4096, 3072, 1024);
    attn_fused<<<dim3(512), dim3(512), 0, stream>>>(qkvb, attnb);
    transpose_cast<<<dim3(1024 / 32, 1024 / 32), dim3(32, 8), 0, stream>>>(Wout, woutT, 1024, 1024);
    gemm_bt<0, 0, 0, 1><<<dim3(1024 / 64, 4096 / 128), dim3(256), 0, stream>>>(
        (const void*)attnb, woutT, bout, (void*)out, 4096, 1024, 1024);
  }
}

// Round 20
// 111.845 us; speedup vs baseline: 1.1478x; 1.1478x over previous
//
#include <hip/hip_runtime.h>
#include <hip/hip_bf16.h>
#include <stdint.h>

typedef __bf16 bf16x8 __attribute__((ext_vector_type(8)));
typedef float  f32x4  __attribute__((ext_vector_type(4)));

typedef __attribute__((address_space(1))) void gas1_t;
typedef __attribute__((address_space(3))) void as3_t;

__device__ __forceinline__ void gload_lds16(const void* g, void* l) {
  // width=16 global->LDS DMA; LDS dest is wave-uniform base + lane*16
  __builtin_amdgcn_global_load_lds((gas1_t*)g, (as3_t*)l, 16, 0, 0);
}

__device__ __forceinline__ f32x4 zero4() { f32x4 z = {0.f, 0.f, 0.f, 0.f}; return z; }

__device__ __forceinline__ unsigned pack_bf16x2(float a, float b) {
  __bf16 ha = (__bf16)a, hb = (__bf16)b;
  unsigned short ua = *(unsigned short*)&ha, ub = *(unsigned short*)&hb;
  return (unsigned)ua | ((unsigned)ub << 16);
}

// native 2^x: single v_exp_f32 (ISA section 3: v_exp_f32 computes 2^S0)
__device__ __forceinline__ float fast_exp2(float x) {
  float r;
  asm("v_exp_f32 %0, %1" : "=v"(r) : "v"(x));
  return r;
}

// ---------------- float -> bf16 cast, 8 elems/thread ----------------
__global__ void cvt_f32_to_bf16(const float* __restrict__ in, __bf16* __restrict__ out, int n) {
  int i = (blockIdx.x * 256 + threadIdx.x) * 8;
  if (i >= n) return;
  const f32x4 v0 = *(const f32x4*)(in + i);
  const f32x4 v1 = *(const f32x4*)(in + i + 4);
  bf16x8 o;
#pragma unroll
  for (int j = 0; j < 4; ++j) { o[j] = (__bf16)v0[j]; o[j + 4] = (__bf16)v1[j]; }
  *(bf16x8*)(out + i) = o;
}

// ---------------- transpose + cast: W[K][N] f32 -> WT[N][K] bf16 ----------------
__global__ void transpose_cast(const float* __restrict__ W, __bf16* __restrict__ WT,
                               int K, int N) {
  __shared__ float tile[32][33];
  const int n0 = blockIdx.x * 32, k0 = blockIdx.y * 32;
  const int tx = threadIdx.x, ty = threadIdx.y;
  for (int i = ty; i < 32; i += 8) tile[i][tx] = W[(size_t)(k0 + i) * N + n0 + tx];
  __syncthreads();
  for (int i = ty; i < 32; i += 8) WT[(size_t)(n0 + i) * K + k0 + tx] = (__bf16)tile[tx][i];
}

// ---------------- merged prep (big_ws path): cvt(x) + transpose(Wqkv) + transpose(Wout) ----
// grid 6144 x 256: [0,2048) cvt 8/thread; [2048,5120) Wqkv tiles; [5120,6144) Wout tiles.
__global__ __launch_bounds__(256) void prep_all(const float* __restrict__ x, __bf16* __restrict__ xb,
                                                const float* __restrict__ Wqkv, __bf16* __restrict__ wqkvT,
                                                const float* __restrict__ Wout, __bf16* __restrict__ woutT) {
  const int bid = blockIdx.x;
  if (bid < 2048) {
    const int i = (bid * 256 + threadIdx.x) * 8;
    const f32x4 v0 = *(const f32x4*)(x + i);
    const f32x4 v1 = *(const f32x4*)(x + i + 4);
    bf16x8 o;
#pragma unroll
    for (int j = 0; j < 4; ++j) { o[j] = (__bf16)v0[j]; o[j + 4] = (__bf16)v1[j]; }
    *(bf16x8*)(xb + i) = o;
    return;
  }
  __shared__ float tile[32][33];
  const int tx = threadIdx.x & 31, ty = threadIdx.x >> 5;
  const float* W; __bf16* WT; int N, n0, k0;
  if (bid < 5120) {
    const int l = bid - 2048;                      // 3072 tiles: [96 n-tiles][32 k-tiles]
    W = Wqkv; WT = wqkvT; N = 3072;
    n0 = (l % 96) * 32; k0 = (l / 96) * 32;
  } else {
    const int l = bid - 5120;                      // 1024 tiles: [32][32]
    W = Wout; WT = woutT; N = 1024;
    n0 = (l & 31) * 32; k0 = (l >> 5) * 32;
  }
  for (int i = ty; i < 32; i += 8) tile[i][tx] = W[(size_t)(k0 + i) * N + n0 + tx];
  __syncthreads();
  for (int i = ty; i < 32; i += 8) WT[(size_t)(n0 + i) * 1024 + k0 + tx] = (__bf16)tile[tx][i];
}

// ---------------- GEMM: C[M][N] = A[M][K] @ BT[N][K]^T + bias ----------------
// SCALE_Q: multiply columns < 1024 by 0.125*log2(e). BN64: 128x64 tile (waves 2x2,
// each 64x32) -> 2x the blocks (occupancy fix for tiny grids ONLY, e.g. GEMM2).
template <int OUT_BF16, int A_F32, int SCALE_Q, int BN64>
__global__ __launch_bounds__(256) void gemm_bt(const void* __restrict__ Ap,
                                               const __bf16* __restrict__ BT,
                                               const float* __restrict__ bias,
                                               void* __restrict__ Cout,
                                               int M, int N, int K) {
  __shared__ __bf16 As[2][4096];                 // [128][32] bf16, linear
  __shared__ __bf16 Bs[2][BN64 ? 2048 : 4096];   // [BN][32] bf16, linear
  const int tid = threadIdx.x;
  const int lane = tid & 63, w = tid >> 6;
  const int wr = w >> 1, wc = w & 1;
  const int lgrp = lane >> 4, lcol = lane & 15;
  const int BN = BN64 ? 64 : 128;
  const int WCS = BN64 ? 32 : 64;                // wave column span
  const int NN = BN64 ? 2 : 4;                   // 16-col subtiles per wave
  const int m0 = blockIdx.y * 128, n0 = blockIdx.x * BN;

  f32x4 acc[4][BN64 ? 2 : 4];
#pragma unroll
  for (int m = 0; m < 4; ++m)
#pragma unroll
    for (int n = 0; n < NN; ++n) acc[m][n] = zero4();

  const int nk = K >> 5;

  auto stageB = [&](int buf, int k0) {
    if (BN64) {
      const int c = tid;                          // 256 chunks = 64 rows x 4
      const int row = c >> 2, kc = (c & 3) * 8;
      const int ldsoff = (w * 64) * 16;           // wave-uniform
      gload_lds16(BT + (size_t)(n0 + row) * K + k0 + kc, (char*)&Bs[buf][0] + ldsoff);
    } else {
#pragma unroll
      for (int q = 0; q < 2; ++q) {
        const int c = q * 256 + w * 64 + lane;
        const int row = c >> 2, kc = (c & 3) * 8;
        const int ldsoff = (q * 256 + w * 64) * 16;
        gload_lds16(BT + (size_t)(n0 + row) * K + k0 + kc, (char*)&Bs[buf][0] + ldsoff);
      }
    }
  };
  auto stageA = [&](int buf, int k0) {
    if (A_F32) {
      const float* A = (const float*)Ap;
      const int c0 = tid * 2;
      const int row = c0 >> 2, kc = (c0 & 3) * 8;
      const float* src = A + (size_t)(m0 + row) * K + k0 + kc;
      const f32x4 v0 = *(const f32x4*)(src);
      const f32x4 v1 = *(const f32x4*)(src + 4);
      const f32x4 v2 = *(const f32x4*)(src + 8);
      const f32x4 v3 = *(const f32x4*)(src + 12);
      bf16x8 o0, o1;
#pragma unroll
      for (int j = 0; j < 4; ++j) {
        o0[j] = (__bf16)v0[j]; o0[j + 4] = (__bf16)v1[j];
        o1[j] = (__bf16)v2[j]; o1[j + 4] = (__bf16)v3[j];
      }
      *(bf16x8*)((char*)&As[buf][0] + c0 * 16) = o0;
      *(bf16x8*)((char*)&As[buf][0] + c0 * 16 + 16) = o1;
    } else {
      const __bf16* A = (const __bf16*)Ap;
#pragma unroll
      for (int q = 0; q < 2; ++q) {
        const int c = q * 256 + w * 64 + lane;
        const int row = c >> 2, kc = (c & 3) * 8;
        const int ldsoff = (q * 256 + w * 64) * 16;
        gload_lds16(A + (size_t)(m0 + row) * K + k0 + kc, (char*)&As[buf][0] + ldsoff);
      }
    }
  };

  stageA(0, 0);
  stageB(0, 0);
  __syncthreads();
  int cur = 0;
  for (int t = 0; t < nk; ++t) {
    if (t + 1 < nk) { stageA(cur ^ 1, (t + 1) * 32); stageB(cur ^ 1, (t + 1) * 32); }
    bf16x8 af[4], bfr[BN64 ? 2 : 4];
#pragma unroll
    for (int m = 0; m < 4; ++m)
      af[m] = *(const bf16x8*)&As[cur][(wr * 64 + m * 16 + lcol) * 32 + lgrp * 8];
#pragma unroll
    for (int n = 0; n < NN; ++n)
      bfr[n] = *(const bf16x8*)&Bs[cur][(wc * WCS + n * 16 + lcol) * 32 + lgrp * 8];
    __builtin_amdgcn_s_setprio(1);
#pragma unroll
    for (int m = 0; m < 4; ++m)
#pragma unroll
      for (int n = 0; n < NN; ++n)
        acc[m][n] = __builtin_amdgcn_mfma_f32_16x16x32_bf16(af[m], bfr[n], acc[m][n], 0, 0, 0);
    __builtin_amdgcn_s_setprio(0);
    __syncthreads();
    cur ^= 1;
  }

#pragma unroll
  for (int m = 0; m < 4; ++m) {
#pragma unroll
    for (int n = 0; n < NN; ++n) {
      const int col = n0 + wc * WCS + n * 16 + lcol;
      const float bv = bias[col];
#pragma unroll
      for (int r = 0; r < 4; ++r) {
        const int row = m0 + wr * 64 + m * 16 + lgrp * 4 + r;
        float v = acc[m][n][r] + bv;
        if (SCALE_Q && col < 1024) v *= 0.18033688011112042f;  // log2(e)/8
        if (OUT_BF16)
          ((__bf16*)Cout)[(size_t)row * N + col] = (__bf16)v;
        else
          ((float*)Cout)[(size_t)row * N + col] = v;
      }
    }
  }
}

// ---------------- fused causal flash attention (v13 = XCD affinity + fixed pairing) ----
// Flat grid 512; xcd = id&7 owns bh in [4*xcd, 4*xcd+4) (2MB K/V per L2 -> L2-resident,
// FETCH drop verified in R19). Pair balance: co-resident blocks differ in kk by 32 ->
// sel=kk>>4 differs by 2 -> xp reversal keyed on sel&2 gives complementary (17-round)
// CU pairs. Block owns 128 q-rows (8 waves x 16), KV tile = 128 (two 64-halves).
// Swapped-operand MFMA, in-register softmax (native v_exp_f32), merged PV, defer-max.
__global__ __launch_bounds__(512, 4) void attn_fused(const __bf16* __restrict__ qkv,
                                                     __bf16* __restrict__ attnb) {
  __shared__ __bf16 Kl[2][64][80];    // K halves [kv][d]
  __shared__ __bf16 Vt[2][64][80];    // V^T halves [d][kv], colblk ^= (kv>>3)&7
  __shared__ __bf16 Pl[8][16][144];   // per-wave P^T [q][kv 0..127], group ^= (q>>2)&3
  const int tid = threadIdx.x, lane = tid & 63, w = tid >> 6;
  const int lgrp = lane >> 4, lcol = lane & 15;
  // XCD-affine bijection: id -> (xcd, sel, xv); bh = 4*xcd + sel; xp reversed on sel&2
  const int id = blockIdx.x;
  const int xcd = id & 7, kk = id >> 3;
  const int sel = kk >> 4, xv = kk & 15;
  const int bh = (xcd << 2) | sel;                // 4 bh per XCD
  const int xp = (sel & 2) ? (15 - xv) : xv;      // complementary CU pairs
  const int b = bh >> 4, h = bh & 15;
  const __bf16* base = qkv + (size_t)b * 2048 * 3072;

  const int qb = xp * 128;            // block q start
  const int rw = qb + w * 16;         // wave q start
  const int nkv = xp + 1;             // number of 128-kv rounds

  // staging: thread covers K/V rows krow and krow+64, cols d00..d00+7
  const int krow = tid >> 3;          // 0..63
  const int d00 = (tid & 7) * 8;
  const int vcol = ((((krow >> 3) ^ (tid & 7)) << 3) | (krow & 7));  // Vt swizzle
  const __bf16* kvp = base + 1024 + h * 64 + d00;

  // Q fragment (B-operand): col = q = lcol, k(d) = lgrp*8 + j (+32 per slice)
  const int q_l = rw + lcol;          // this lane's q-row
  const __bf16* qptr = base + (size_t)q_l * 3072 + h * 64;
  const bf16x8 qf0 = *(const bf16x8*)(qptr + lgrp * 8);
  const bf16x8 qf1 = *(const bf16x8*)(qptr + 32 + lgrp * 8);

  float m1 = -1e30f, l1 = 0.f;        // own-row softmax state (log2 domain)
  f32x4 acc_o[4];                     // O^T: row d = dsub*16 + 4*lgrp + r
#pragma unroll
  for (int d = 0; d < 4; ++d) acc_o[d] = zero4();

  // prefetch round 0 (2 K-vecs + 2 V-vecs per thread)
  bf16x8 kf0 = *(const bf16x8*)(kvp + (size_t)krow * 3072);
  bf16x8 vf0 = *(const bf16x8*)(kvp + (size_t)krow * 3072 + 1024);
  bf16x8 kf1 = *(const bf16x8*)(kvp + (size_t)(krow + 64) * 3072);
  bf16x8 vf1 = *(const bf16x8*)(kvp + (size_t)(krow + 64) * 3072 + 1024);

  for (int kvb = 0; kvb < nkv; ++kvb) {
    const int kv0 = kvb * 128;
    __syncthreads();  // previous round's LDS reads complete
    *(bf16x8*)&Kl[0][krow][d00] = kf0;
    *(bf16x8*)&Kl[1][krow][d00] = kf1;
#pragma unroll
    for (int j = 0; j < 8; ++j) {
      Vt[0][d00 + j][vcol] = vf0[j];
      Vt[1][d00 + j][vcol] = vf1[j];
    }
    __syncthreads();
    // issue next round's global loads (latency hides under compute below)
    if (kvb + 1 < nkv) {
      const __bf16* p = kvp + (size_t)(kv0 + 128 + krow) * 3072;
      kf0 = *(const bf16x8*)p;
      vf0 = *(const bf16x8*)(p + 1024);
      kf1 = *(const bf16x8*)(p + (size_t)64 * 3072);
      vf1 = *(const bf16x8*)(p + (size_t)64 * 3072 + 1024);
    }

    const bool diag = (kvb == xp);          // only final round needs masking
    const bool skip1 = diag && (w < 4);     // waves 0-3: upper kv-half fully masked

    // S^T = K @ Q : D col = q = lcol, row = kv = sub*16 + 4*lgrp + r
    f32x4 accs[8];
    __builtin_amdgcn_s_setprio(1);
#pragma unroll
    for (int sub = 0; sub < 4; ++sub) {
      accs[sub] = zero4();
#pragma unroll
      for (int s = 0; s < 2; ++s) {
        const bf16x8 kb = *(const bf16x8*)&Kl[0][sub * 16 + lcol][s * 32 + lgrp * 8];
        accs[sub] = __builtin_amdgcn_mfma_f32_16x16x32_bf16(kb, s ? qf1 : qf0, accs[sub], 0, 0, 0);
      }
    }
    if (!skip1) {
#pragma unroll
      for (int sub = 0; sub < 4; ++sub) {
        accs[4 + sub] = zero4();
#pragma unroll
        for (int s = 0; s < 2; ++s) {
          const bf16x8 kb = *(const bf16x8*)&Kl[1][sub * 16 + lcol][s * 32 + lgrp * 8];
          accs[4 + sub] = __builtin_amdgcn_mfma_f32_16x16x32_bf16(kb, s ? qf1 : qf0, accs[4 + sub], 0, 0, 0);
        }
      }
    } else {
#pragma unroll
      for (int sub = 4; sub < 8; ++sub) accs[sub] = f32x4{-1e30f, -1e30f, -1e30f, -1e30f};
    }
    __builtin_amdgcn_s_setprio(0);

    // causal mask (diagonal round only); Q already carries scale
    if (diag) {
#pragma unroll
      for (int sub = 0; sub < 8; ++sub) {
        const int kvg = kv0 + sub * 16 + lgrp * 4;
#pragma unroll
        for (int r = 0; r < 4; ++r)
          if (kvg + r > q_l) accs[sub][r] = -1e30f;
      }
    }

    // in-register row max (tree) + 2 shfl across the 4 lanes sharing this row
    float mx[8];
#pragma unroll
    for (int sub = 0; sub < 8; ++sub)
      mx[sub] = fmaxf(fmaxf(accs[sub][0], accs[sub][1]), fmaxf(accs[sub][2], accs[sub][3]));
    float rm = fmaxf(fmaxf(fmaxf(mx[0], mx[1]), fmaxf(mx[2], mx[3])),
                     fmaxf(fmaxf(mx[4], mx[5]), fmaxf(mx[6], mx[7])));
    rm = fmaxf(rm, __shfl_xor(rm, 16));
    rm = fmaxf(rm, __shfl_xor(rm, 32));

    // T13 defer-max: only rescale when the new tile max exceeds m1 by > 8
    if (!__all(rm - m1 <= 8.0f)) {
      const float nm = fmaxf(m1, rm);
      const float sf = fast_exp2(m1 - nm);
      m1 = nm;
      l1 *= sf;
#pragma unroll
      for (int d = 0; d < 4; ++d)
#pragma unroll
        for (int r = 0; r < 4; ++r) acc_o[d][r] *= sf;
    }

    // exp2 in place (native v_exp_f32) + row sum (tree) + 2 shfl
    float ps[8];
#pragma unroll
    for (int sub = 0; sub < 8; ++sub) {
#pragma unroll
      for (int r = 0; r < 4; ++r) accs[sub][r] = fast_exp2(accs[sub][r] - m1);
      ps[sub] = (accs[sub][0] + accs[sub][1]) + (accs[sub][2] + accs[sub][3]);
    }
    float rs = ((ps[0] + ps[1]) + (ps[2] + ps[3])) + ((ps[4] + ps[5]) + (ps[6] + ps[7]));
    rs += __shfl_xor(rs, 16);
    rs += __shfl_xor(rs, 32);
    l1 += rs;

    // ---- merged PV: store P for BOTH halves, one waitcnt, one 16-MFMA run ----
#pragma unroll
    for (int sub = 0; sub < 4; ++sub) {
      uint2 pk;
      pk.x = pack_bf16x2(accs[sub][0], accs[sub][1]);
      pk.y = pack_bf16x2(accs[sub][2], accs[sub][3]);
      const int eoff = ((((sub * 2 + (lgrp >> 1)) ^ ((lcol >> 2) & 3)) << 3) | ((lgrp & 1) << 2));
      *(uint2*)&Pl[w][lcol][eoff] = pk;
    }
    if (!skip1) {
#pragma unroll
      for (int sub = 4; sub < 8; ++sub) {
        uint2 pk;
        pk.x = pack_bf16x2(accs[sub][0], accs[sub][1]);
        pk.y = pack_bf16x2(accs[sub][2], accs[sub][3]);
        const int eoff = ((((sub * 2 + (lgrp >> 1)) ^ ((lcol >> 2) & 3)) << 3) | ((lgrp & 1) << 2));
        *(uint2*)&Pl[w][lcol][eoff] = pk;
      }
    }
    asm volatile("s_waitcnt lgkmcnt(0)" ::: "memory");
    __builtin_amdgcn_sched_barrier(0);  // rule 18
    __builtin_amdgcn_s_setprio(1);
#pragma unroll
    for (int s = 0; s < 2; ++s) {
      const bf16x8 pf = *(const bf16x8*)&Pl[w][lcol][((4 * s + lgrp) ^ ((lcol >> 2) & 3)) * 8];
#pragma unroll
      for (int d = 0; d < 4; ++d) {
        const bf16x8 vfr = *(const bf16x8*)&Vt[0][d * 16 + lcol][((4 * s + lgrp) ^ ((2 * d + (lcol >> 3)) & 7)) * 8];
        acc_o[d] = __builtin_amdgcn_mfma_f32_16x16x32_bf16(vfr, pf, acc_o[d], 0, 0, 0);
      }
    }
    if (!skip1) {
#pragma unroll
      for (int s = 2; s < 4; ++s) {
        const bf16x8 pf = *(const bf16x8*)&Pl[w][lcol][((4 * s + lgrp) ^ ((lcol >> 2) & 3)) * 8];
#pragma unroll
        for (int d = 0; d < 4; ++d) {
          const bf16x8 vfr = *(const bf16x8*)&Vt[1][d * 16 + lcol][((4 * (s - 2) + lgrp) ^ ((2 * d + (lcol >> 3)) & 7)) * 8];
          acc_o[d] = __builtin_amdgcn_mfma_f32_16x16x32_bf16(vfr, pf, acc_o[d], 0, 0, 0);
        }
      }
    }
    __builtin_amdgcn_s_setprio(0);
  }

  // epilogue: O^T -> bf16 [B*T][1024]; lane owns q-row q_l, d = dsub*16+4*lgrp+{0..3}
  const float inv_l = 1.0f / l1;
  __bf16* orow = attnb + (size_t)(b * 2048 + q_l) * 1024 + h * 64 + lgrp * 4;
#pragma unroll
  for (int d = 0; d < 4; ++d) {
    uint2 ov;
    ov.x = pack_bf16x2(acc_o[d][0] * inv_l, acc_o[d][1] * inv_l);
    ov.y = pack_bf16x2(acc_o[d][2] * inv_l, acc_o[d][3] * inv_l);
    *(uint2*)(orow + d * 16) = ov;
  }
}

extern "C" void kernel_launch(void* const* d_in, const int* in_sizes, int n_in,
                              void* d_out, int out_size, void* d_ws, size_t ws_size,
                              hipStream_t stream) {
  const float* x    = (const float*)d_in[0];
  const float* Wqkv = (const float*)d_in[1];
  const float* bqkv = (const float*)d_in[2];
  const float* Wout = (const float*)d_in[3];
  const float* bout = (const float*)d_in[4];
  float* out = (float*)d_out;

  // Workspace plan (big_ws, >= 40MB):
  //   [0,24M)   qkvb  (bf16 [4096][3072])  -- dead after attn
  //   [24,30M)  wqkvT (bf16 [3072][1024])
  //   [30,38M)  xb    (bf16 [4096][1024])
  //   [38,40M)  woutT (bf16 [1024][1024])  -- no alias (prep runs before GEMM1)
  //   [24,32M)  attnb (bf16 [4096][1024])  -- over dead wqkvT
  // small_ws fallback (32MB peak): woutT over dead qkvb.
  char* ws = (char*)d_ws;
  __bf16* qkvb  = (__bf16*)(ws);
  __bf16* wqkvT = (__bf16*)(ws + (24u << 20));
  __bf16* xb    = (__bf16*)(ws + (30u << 20));
  __bf16* attnb = (__bf16*)(ws + (24u << 20));

  const bool big_ws = ws_size >= ((size_t)40 << 20);

  if (big_ws) {
    __bf16* woutT = (__bf16*)(ws + (38u << 20));
    prep_all<<<dim3(2048 + 3072 + 1024), dim3(256), 0, stream>>>(x, xb, Wqkv, wqkvT, Wout, woutT);
    // QKV-proj: proven BN128 path (3 blocks/CU, highest compute density)
    gemm_bt<1, 0, 1, 0><<<dim3(3072 / 128, 4096 / 128), dim3(256), 0, stream>>>(
        (const void*)xb, wqkvT, bqkv, (void*)qkvb, 4096, 3072, 1024);
    attn_fused<<<dim3(512), dim3(512), 0, stream>>>(qkvb, attnb);
    // out-proj: BN64 (512 blocks = 2 blocks/CU fixes occupancy-1 drain exposure)
    gemm_bt<0, 0, 0, 1><<<dim3(1024 / 64, 4096 / 128), dim3(256), 0, stream>>>(
        (const void*)attnb, woutT, bout, (void*)out, 4096, 1024, 1024);
  } else {
    __bf16* woutT = (__bf16*)(ws);
    transpose_cast<<<dim3(3072 / 32, 1024 / 32), dim3(32, 8), 0, stream>>>(Wqkv, wqkvT, 1024, 3072);
    gemm_bt<1, 1, 1, 0><<<dim3(3072 / 128, 4096 / 128), dim3(256), 0, stream>>>(
        (const void*)x, wqkvT, bqkv, (void*)qkvb, 4096, 3072, 1024);
    attn_fused<<<dim3(512), dim3(512), 0, stream>>>(qkvb, attnb);
    transpose_cast<<<dim3(1024 / 32, 1024 / 32), dim3(32, 8), 0, stream>>>(Wout, woutT, 1024, 1024);
    gemm_bt<0, 0, 0, 1><<<dim3(1024 / 64, 4096 / 128), dim3(256), 0, stream>>>(
        (const void*)attnb, woutT, bout, (void*)out, 4096, 1024, 1024);
  }
}

// Round 21
// 111.441 us; speedup vs baseline: 1.1519x; 1.0036x over previous
//
#include <hip/hip_runtime.h>
#include <hip/hip_bf16.h>
#include <stdint.h>

typedef __bf16 bf16x8 __attribute__((ext_vector_type(8)));
typedef float  f32x4  __attribute__((ext_vector_type(4)));

typedef __attribute__((address_space(1))) void gas1_t;
typedef __attribute__((address_space(3))) void as3_t;

__device__ __forceinline__ void gload_lds16(const void* g, void* l) {
  // width=16 global->LDS DMA; LDS dest is wave-uniform base + lane*16
  __builtin_amdgcn_global_load_lds((gas1_t*)g, (as3_t*)l, 16, 0, 0);
}

__device__ __forceinline__ f32x4 zero4() { f32x4 z = {0.f, 0.f, 0.f, 0.f}; return z; }

__device__ __forceinline__ unsigned pack_bf16x2(float a, float b) {
  __bf16 ha = (__bf16)a, hb = (__bf16)b;
  unsigned short ua = *(unsigned short*)&ha, ub = *(unsigned short*)&hb;
  return (unsigned)ua | ((unsigned)ub << 16);
}

// native 2^x: single v_exp_f32 (ISA section 3: v_exp_f32 computes 2^S0)
__device__ __forceinline__ float fast_exp2(float x) {
  float r;
  asm("v_exp_f32 %0, %1" : "=v"(r) : "v"(x));
  return r;
}

// ---------------- float -> bf16 cast, 8 elems/thread ----------------
__global__ void cvt_f32_to_bf16(const float* __restrict__ in, __bf16* __restrict__ out, int n) {
  int i = (blockIdx.x * 256 + threadIdx.x) * 8;
  if (i >= n) return;
  const f32x4 v0 = *(const f32x4*)(in + i);
  const f32x4 v1 = *(const f32x4*)(in + i + 4);
  bf16x8 o;
#pragma unroll
  for (int j = 0; j < 4; ++j) { o[j] = (__bf16)v0[j]; o[j + 4] = (__bf16)v1[j]; }
  *(bf16x8*)(out + i) = o;
}

// ---------------- transpose + cast: W[K][N] f32 -> WT[N][K] bf16 ----------------
__global__ void transpose_cast(const float* __restrict__ W, __bf16* __restrict__ WT,
                               int K, int N) {
  __shared__ float tile[32][33];
  const int n0 = blockIdx.x * 32, k0 = blockIdx.y * 32;
  const int tx = threadIdx.x, ty = threadIdx.y;
  for (int i = ty; i < 32; i += 8) tile[i][tx] = W[(size_t)(k0 + i) * N + n0 + tx];
  __syncthreads();
  for (int i = ty; i < 32; i += 8) WT[(size_t)(n0 + i) * K + k0 + tx] = (__bf16)tile[tx][i];
}

// ---------------- merged prep (big_ws path): cvt(x) + transpose(Wqkv) + transpose(Wout) ----
// grid 6144 x 256: [0,2048) cvt 8/thread; [2048,5120) Wqkv tiles; [5120,6144) Wout tiles.
__global__ __launch_bounds__(256) void prep_all(const float* __restrict__ x, __bf16* __restrict__ xb,
                                                const float* __restrict__ Wqkv, __bf16* __restrict__ wqkvT,
                                                const float* __restrict__ Wout, __bf16* __restrict__ woutT) {
  const int bid = blockIdx.x;
  if (bid < 2048) {
    const int i = (bid * 256 + threadIdx.x) * 8;
    const f32x4 v0 = *(const f32x4*)(x + i);
    const f32x4 v1 = *(const f32x4*)(x + i + 4);
    bf16x8 o;
#pragma unroll
    for (int j = 0; j < 4; ++j) { o[j] = (__bf16)v0[j]; o[j + 4] = (__bf16)v1[j]; }
    *(bf16x8*)(xb + i) = o;
    return;
  }
  __shared__ float tile[32][33];
  const int tx = threadIdx.x & 31, ty = threadIdx.x >> 5;
  const float* W; __bf16* WT; int N, n0, k0;
  if (bid < 5120) {
    const int l = bid - 2048;                      // 3072 tiles: [96 n-tiles][32 k-tiles]
    W = Wqkv; WT = wqkvT; N = 3072;
    n0 = (l % 96) * 32; k0 = (l / 96) * 32;
  } else {
    const int l = bid - 5120;                      // 1024 tiles: [32][32]
    W = Wout; WT = woutT; N = 1024;
    n0 = (l & 31) * 32; k0 = (l >> 5) * 32;
  }
  for (int i = ty; i < 32; i += 8) tile[i][tx] = W[(size_t)(k0 + i) * N + n0 + tx];
  __syncthreads();
  for (int i = ty; i < 32; i += 8) WT[(size_t)(n0 + i) * 1024 + k0 + tx] = (__bf16)tile[tx][i];
}

// ---------------- GEMM: C[M][N] = A[M][K] @ BT[N][K]^T + bias ----------------
// SCALE_Q: multiply columns < 1024 by 0.125*log2(e). BN64: 128x64 tile. XCDN: blocks
// launched as flat grid 8*XCDN*(M/128); xcd = id&7 owns XCDN consecutive n-panels
// (B L2-resident) and co-XCD blocks with equal `by` share one A-panel (L2-hit).
template <int OUT_BF16, int A_F32, int SCALE_Q, int BN64, int XCDN>
__global__ __launch_bounds__(256) void gemm_bt(const void* __restrict__ Ap,
                                               const __bf16* __restrict__ BT,
                                               const float* __restrict__ bias,
                                               void* __restrict__ Cout,
                                               int M, int N, int K) {
  __shared__ __bf16 As[2][4096];                 // [128][32] bf16, linear
  __shared__ __bf16 Bs[2][BN64 ? 2048 : 4096];   // [BN][32] bf16, linear
  const int tid = threadIdx.x;
  const int lane = tid & 63, w = tid >> 6;
  const int wr = w >> 1, wc = w & 1;
  const int lgrp = lane >> 4, lcol = lane & 15;
  const int BN = BN64 ? 64 : 128;
  const int WCS = BN64 ? 32 : 64;                // wave column span
  const int NN = BN64 ? 2 : 4;                   // 16-col subtiles per wave
  // XCD-affine bijection: id -> (xcd, k) -> (bx, by)
  const int id = blockIdx.x;
  const int xcd = id & 7, k = id >> 3;
  const int bx = xcd * XCDN + k % XCDN;
  const int by = k / XCDN;
  const int m0 = by * 128, n0 = bx * BN;

  f32x4 acc[4][BN64 ? 2 : 4];
#pragma unroll
  for (int m = 0; m < 4; ++m)
#pragma unroll
    for (int n = 0; n < NN; ++n) acc[m][n] = zero4();

  const int nk = K >> 5;

  auto stageB = [&](int buf, int k0) {
    if (BN64) {
      const int c = tid;                          // 256 chunks = 64 rows x 4
      const int row = c >> 2, kc = (c & 3) * 8;
      const int ldsoff = (w * 64) * 16;           // wave-uniform
      gload_lds16(BT + (size_t)(n0 + row) * K + k0 + kc, (char*)&Bs[buf][0] + ldsoff);
    } else {
#pragma unroll
      for (int q = 0; q < 2; ++q) {
        const int c = q * 256 + w * 64 + lane;
        const int row = c >> 2, kc = (c & 3) * 8;
        const int ldsoff = (q * 256 + w * 64) * 16;
        gload_lds16(BT + (size_t)(n0 + row) * K + k0 + kc, (char*)&Bs[buf][0] + ldsoff);
      }
    }
  };
  auto stageA = [&](int buf, int k0) {
    if (A_F32) {
      const float* A = (const float*)Ap;
      const int c0 = tid * 2;
      const int row = c0 >> 2, kc = (c0 & 3) * 8;
      const float* src = A + (size_t)(m0 + row) * K + k0 + kc;
      const f32x4 v0 = *(const f32x4*)(src);
      const f32x4 v1 = *(const f32x4*)(src + 4);
      const f32x4 v2 = *(const f32x4*)(src + 8);
      const f32x4 v3 = *(const f32x4*)(src + 12);
      bf16x8 o0, o1;
#pragma unroll
      for (int j = 0; j < 4; ++j) {
        o0[j] = (__bf16)v0[j]; o0[j + 4] = (__bf16)v1[j];
        o1[j] = (__bf16)v2[j]; o1[j + 4] = (__bf16)v3[j];
      }
      *(bf16x8*)((char*)&As[buf][0] + c0 * 16) = o0;
      *(bf16x8*)((char*)&As[buf][0] + c0 * 16 + 16) = o1;
    } else {
      const __bf16* A = (const __bf16*)Ap;
#pragma unroll
      for (int q = 0; q < 2; ++q) {
        const int c = q * 256 + w * 64 + lane;
        const int row = c >> 2, kc = (c & 3) * 8;
        const int ldsoff = (q * 256 + w * 64) * 16;
        gload_lds16(A + (size_t)(m0 + row) * K + k0 + kc, (char*)&As[buf][0] + ldsoff);
      }
    }
  };

  stageA(0, 0);
  stageB(0, 0);
  __syncthreads();
  int cur = 0;
  for (int t = 0; t < nk; ++t) {
    if (t + 1 < nk) { stageA(cur ^ 1, (t + 1) * 32); stageB(cur ^ 1, (t + 1) * 32); }
    bf16x8 af[4], bfr[BN64 ? 2 : 4];
#pragma unroll
    for (int m = 0; m < 4; ++m)
      af[m] = *(const bf16x8*)&As[cur][(wr * 64 + m * 16 + lcol) * 32 + lgrp * 8];
#pragma unroll
    for (int n = 0; n < NN; ++n)
      bfr[n] = *(const bf16x8*)&Bs[cur][(wc * WCS + n * 16 + lcol) * 32 + lgrp * 8];
    __builtin_amdgcn_s_setprio(1);
#pragma unroll
    for (int m = 0; m < 4; ++m)
#pragma unroll
      for (int n = 0; n < NN; ++n)
        acc[m][n] = __builtin_amdgcn_mfma_f32_16x16x32_bf16(af[m], bfr[n], acc[m][n], 0, 0, 0);
    __builtin_amdgcn_s_setprio(0);
    __syncthreads();
    cur ^= 1;
  }

#pragma unroll
  for (int m = 0; m < 4; ++m) {
#pragma unroll
    for (int n = 0; n < NN; ++n) {
      const int col = n0 + wc * WCS + n * 16 + lcol;
      const float bv = bias[col];
#pragma unroll
      for (int r = 0; r < 4; ++r) {
        const int row = m0 + wr * 64 + m * 16 + lgrp * 4 + r;
        float v = acc[m][n][r] + bv;
        if (SCALE_Q && col < 1024) v *= 0.18033688011112042f;  // log2(e)/8
        if (OUT_BF16)
          ((__bf16*)Cout)[(size_t)row * N + col] = (__bf16)v;
        else
          ((float*)Cout)[(size_t)row * N + col] = v;
      }
    }
  }
}

// ---------------- fused causal flash attention (v13 = XCD affinity + fixed pairing) ----
// Flat grid 512; xcd = id&7 owns bh in [4*xcd, 4*xcd+4) (2MB K/V per L2 -> L2-resident).
// Pair balance: xp reversal keyed on sel&2 gives complementary (17-round) CU pairs.
// Block owns 128 q-rows (8 waves x 16), KV tile = 128 (two 64-halves).
// Swapped-operand MFMA, in-register softmax (native v_exp_f32), merged PV, defer-max.
__global__ __launch_bounds__(512, 4) void attn_fused(const __bf16* __restrict__ qkv,
                                                     __bf16* __restrict__ attnb) {
  __shared__ __bf16 Kl[2][64][80];    // K halves [kv][d]
  __shared__ __bf16 Vt[2][64][80];    // V^T halves [d][kv], colblk ^= (kv>>3)&7
  __shared__ __bf16 Pl[8][16][144];   // per-wave P^T [q][kv 0..127], group ^= (q>>2)&3
  const int tid = threadIdx.x, lane = tid & 63, w = tid >> 6;
  const int lgrp = lane >> 4, lcol = lane & 15;
  // XCD-affine bijection: id -> (xcd, sel, xv); bh = 4*xcd + sel; xp reversed on sel&2
  const int id = blockIdx.x;
  const int xcd = id & 7, kk = id >> 3;
  const int sel = kk >> 4, xv = kk & 15;
  const int bh = (xcd << 2) | sel;                // 4 bh per XCD
  const int xp = (sel & 2) ? (15 - xv) : xv;      // complementary CU pairs
  const int b = bh >> 4, h = bh & 15;
  const __bf16* base = qkv + (size_t)b * 2048 * 3072;

  const int qb = xp * 128;            // block q start
  const int rw = qb + w * 16;         // wave q start
  const int nkv = xp + 1;             // number of 128-kv rounds

  // staging: thread covers K/V rows krow and krow+64, cols d00..d00+7
  const int krow = tid >> 3;          // 0..63
  const int d00 = (tid & 7) * 8;
  const int vcol = ((((krow >> 3) ^ (tid & 7)) << 3) | (krow & 7));  // Vt swizzle
  const __bf16* kvp = base + 1024 + h * 64 + d00;

  // Q fragment (B-operand): col = q = lcol, k(d) = lgrp*8 + j (+32 per slice)
  const int q_l = rw + lcol;          // this lane's q-row
  const __bf16* qptr = base + (size_t)q_l * 3072 + h * 64;
  const bf16x8 qf0 = *(const bf16x8*)(qptr + lgrp * 8);
  const bf16x8 qf1 = *(const bf16x8*)(qptr + 32 + lgrp * 8);

  float m1 = -1e30f, l1 = 0.f;        // own-row softmax state (log2 domain)
  f32x4 acc_o[4];                     // O^T: row d = dsub*16 + 4*lgrp + r
#pragma unroll
  for (int d = 0; d < 4; ++d) acc_o[d] = zero4();

  // prefetch round 0 (2 K-vecs + 2 V-vecs per thread)
  bf16x8 kf0 = *(const bf16x8*)(kvp + (size_t)krow * 3072);
  bf16x8 vf0 = *(const bf16x8*)(kvp + (size_t)krow * 3072 + 1024);
  bf16x8 kf1 = *(const bf16x8*)(kvp + (size_t)(krow + 64) * 3072);
  bf16x8 vf1 = *(const bf16x8*)(kvp + (size_t)(krow + 64) * 3072 + 1024);

  for (int kvb = 0; kvb < nkv; ++kvb) {
    const int kv0 = kvb * 128;
    __syncthreads();  // previous round's LDS reads complete
    *(bf16x8*)&Kl[0][krow][d00] = kf0;
    *(bf16x8*)&Kl[1][krow][d00] = kf1;
#pragma unroll
    for (int j = 0; j < 8; ++j) {
      Vt[0][d00 + j][vcol] = vf0[j];
      Vt[1][d00 + j][vcol] = vf1[j];
    }
    __syncthreads();
    // issue next round's global loads (latency hides under compute below)
    if (kvb + 1 < nkv) {
      const __bf16* p = kvp + (size_t)(kv0 + 128 + krow) * 3072;
      kf0 = *(const bf16x8*)p;
      vf0 = *(const bf16x8*)(p + 1024);
      kf1 = *(const bf16x8*)(p + (size_t)64 * 3072);
      vf1 = *(const bf16x8*)(p + (size_t)64 * 3072 + 1024);
    }

    const bool diag = (kvb == xp);          // only final round needs masking
    const bool skip1 = diag && (w < 4);     // waves 0-3: upper kv-half fully masked

    // S^T = K @ Q : D col = q = lcol, row = kv = sub*16 + 4*lgrp + r
    f32x4 accs[8];
    __builtin_amdgcn_s_setprio(1);
#pragma unroll
    for (int sub = 0; sub < 4; ++sub) {
      accs[sub] = zero4();
#pragma unroll
      for (int s = 0; s < 2; ++s) {
        const bf16x8 kb = *(const bf16x8*)&Kl[0][sub * 16 + lcol][s * 32 + lgrp * 8];
        accs[sub] = __builtin_amdgcn_mfma_f32_16x16x32_bf16(kb, s ? qf1 : qf0, accs[sub], 0, 0, 0);
      }
    }
    if (!skip1) {
#pragma unroll
      for (int sub = 0; sub < 4; ++sub) {
        accs[4 + sub] = zero4();
#pragma unroll
        for (int s = 0; s < 2; ++s) {
          const bf16x8 kb = *(const bf16x8*)&Kl[1][sub * 16 + lcol][s * 32 + lgrp * 8];
          accs[4 + sub] = __builtin_amdgcn_mfma_f32_16x16x32_bf16(kb, s ? qf1 : qf0, accs[4 + sub], 0, 0, 0);
        }
      }
    } else {
#pragma unroll
      for (int sub = 4; sub < 8; ++sub) accs[sub] = f32x4{-1e30f, -1e30f, -1e30f, -1e30f};
    }
    __builtin_amdgcn_s_setprio(0);

    // causal mask (diagonal round only); Q already carries scale
    if (diag) {
#pragma unroll
      for (int sub = 0; sub < 8; ++sub) {
        const int kvg = kv0 + sub * 16 + lgrp * 4;
#pragma unroll
        for (int r = 0; r < 4; ++r)
          if (kvg + r > q_l) accs[sub][r] = -1e30f;
      }
    }

    // in-register row max (tree) + 2 shfl across the 4 lanes sharing this row
    float mx[8];
#pragma unroll
    for (int sub = 0; sub < 8; ++sub)
      mx[sub] = fmaxf(fmaxf(accs[sub][0], accs[sub][1]), fmaxf(accs[sub][2], accs[sub][3]));
    float rm = fmaxf(fmaxf(fmaxf(mx[0], mx[1]), fmaxf(mx[2], mx[3])),
                     fmaxf(fmaxf(mx[4], mx[5]), fmaxf(mx[6], mx[7])));
    rm = fmaxf(rm, __shfl_xor(rm, 16));
    rm = fmaxf(rm, __shfl_xor(rm, 32));

    // T13 defer-max: only rescale when the new tile max exceeds m1 by > 8
    if (!__all(rm - m1 <= 8.0f)) {
      const float nm = fmaxf(m1, rm);
      const float sf = fast_exp2(m1 - nm);
      m1 = nm;
      l1 *= sf;
#pragma unroll
      for (int d = 0; d < 4; ++d)
#pragma unroll
        for (int r = 0; r < 4; ++r) acc_o[d][r] *= sf;
    }

    // exp2 in place (native v_exp_f32) + row sum (tree) + 2 shfl
    float ps[8];
#pragma unroll
    for (int sub = 0; sub < 8; ++sub) {
#pragma unroll
      for (int r = 0; r < 4; ++r) accs[sub][r] = fast_exp2(accs[sub][r] - m1);
      ps[sub] = (accs[sub][0] + accs[sub][1]) + (accs[sub][2] + accs[sub][3]);
    }
    float rs = ((ps[0] + ps[1]) + (ps[2] + ps[3])) + ((ps[4] + ps[5]) + (ps[6] + ps[7]));
    rs += __shfl_xor(rs, 16);
    rs += __shfl_xor(rs, 32);
    l1 += rs;

    // ---- merged PV: store P for BOTH halves, one waitcnt, one 16-MFMA run ----
#pragma unroll
    for (int sub = 0; sub < 4; ++sub) {
      uint2 pk;
      pk.x = pack_bf16x2(accs[sub][0], accs[sub][1]);
      pk.y = pack_bf16x2(accs[sub][2], accs[sub][3]);
      const int eoff = ((((sub * 2 + (lgrp >> 1)) ^ ((lcol >> 2) & 3)) << 3) | ((lgrp & 1) << 2));
      *(uint2*)&Pl[w][lcol][eoff] = pk;
    }
    if (!skip1) {
#pragma unroll
      for (int sub = 4; sub < 8; ++sub) {
        uint2 pk;
        pk.x = pack_bf16x2(accs[sub][0], accs[sub][1]);
        pk.y = pack_bf16x2(accs[sub][2], accs[sub][3]);
        const int eoff = ((((sub * 2 + (lgrp >> 1)) ^ ((lcol >> 2) & 3)) << 3) | ((lgrp & 1) << 2));
        *(uint2*)&Pl[w][lcol][eoff] = pk;
      }
    }
    asm volatile("s_waitcnt lgkmcnt(0)" ::: "memory");
    __builtin_amdgcn_sched_barrier(0);  // rule 18
    __builtin_amdgcn_s_setprio(1);
#pragma unroll
    for (int s = 0; s < 2; ++s) {
      const bf16x8 pf = *(const bf16x8*)&Pl[w][lcol][((4 * s + lgrp) ^ ((lcol >> 2) & 3)) * 8];
#pragma unroll
      for (int d = 0; d < 4; ++d) {
        const bf16x8 vfr = *(const bf16x8*)&Vt[0][d * 16 + lcol][((4 * s + lgrp) ^ ((2 * d + (lcol >> 3)) & 7)) * 8];
        acc_o[d] = __builtin_amdgcn_mfma_f32_16x16x32_bf16(vfr, pf, acc_o[d], 0, 0, 0);
      }
    }
    if (!skip1) {
#pragma unroll
      for (int s = 2; s < 4; ++s) {
        const bf16x8 pf = *(const bf16x8*)&Pl[w][lcol][((4 * s + lgrp) ^ ((lcol >> 2) & 3)) * 8];
#pragma unroll
        for (int d = 0; d < 4; ++d) {
          const bf16x8 vfr = *(const bf16x8*)&Vt[1][d * 16 + lcol][((4 * (s - 2) + lgrp) ^ ((2 * d + (lcol >> 3)) & 7)) * 8];
          acc_o[d] = __builtin_amdgcn_mfma_f32_16x16x32_bf16(vfr, pf, acc_o[d], 0, 0, 0);
        }
      }
    }
    __builtin_amdgcn_s_setprio(0);
  }

  // epilogue: O^T -> bf16 [B*T][1024]; lane owns q-row q_l, d = dsub*16+4*lgrp+{0..3}
  const float inv_l = 1.0f / l1;
  __bf16* orow = attnb + (size_t)(b * 2048 + q_l) * 1024 + h * 64 + lgrp * 4;
#pragma unroll
  for (int d = 0; d < 4; ++d) {
    uint2 ov;
    ov.x = pack_bf16x2(acc_o[d][0] * inv_l, acc_o[d][1] * inv_l);
    ov.y = pack_bf16x2(acc_o[d][2] * inv_l, acc_o[d][3] * inv_l);
    *(uint2*)(orow + d * 16) = ov;
  }
}

extern "C" void kernel_launch(void* const* d_in, const int* in_sizes, int n_in,
                              void* d_out, int out_size, void* d_ws, size_t ws_size,
                              hipStream_t stream) {
  const float* x    = (const float*)d_in[0];
  const float* Wqkv = (const float*)d_in[1];
  const float* bqkv = (const float*)d_in[2];
  const float* Wout = (const float*)d_in[3];
  const float* bout = (const float*)d_in[4];
  float* out = (float*)d_out;

  // Workspace plan (big_ws, >= 40MB):
  //   [0,24M)   qkvb  (bf16 [4096][3072])  -- dead after attn
  //   [24,30M)  wqkvT (bf16 [3072][1024])
  //   [30,38M)  xb    (bf16 [4096][1024])
  //   [38,40M)  woutT (bf16 [1024][1024])  -- no alias (prep runs before GEMM1)
  //   [24,32M)  attnb (bf16 [4096][1024])  -- over dead wqkvT
  // small_ws fallback (32MB peak): woutT over dead qkvb.
  char* ws = (char*)d_ws;
  __bf16* qkvb  = (__bf16*)(ws);
  __bf16* wqkvT = (__bf16*)(ws + (24u << 20));
  __bf16* xb    = (__bf16*)(ws + (30u << 20));
  __bf16* attnb = (__bf16*)(ws + (24u << 20));

  const bool big_ws = ws_size >= ((size_t)40 << 20);

  if (big_ws) {
    __bf16* woutT = (__bf16*)(ws + (38u << 20));
    prep_all<<<dim3(2048 + 3072 + 1024), dim3(256), 0, stream>>>(x, xb, Wqkv, wqkvT, Wout, woutT);
    // QKV-proj: BN128, XCD-affine (xcd owns 3 n-panels; co-XCD trios share A-panel)
    gemm_bt<1, 0, 1, 0, 3><<<dim3(768), dim3(256), 0, stream>>>(
        (const void*)xb, wqkvT, bqkv, (void*)qkvb, 4096, 3072, 1024);
    attn_fused<<<dim3(512), dim3(512), 0, stream>>>(qkvb, attnb);
    // out-proj: BN64, XCD-affine (xcd owns 2 n-panels)
    gemm_bt<0, 0, 0, 1, 2><<<dim3(512), dim3(256), 0, stream>>>(
        (const void*)attnb, woutT, bout, (void*)out, 4096, 1024, 1024);
  } else {
    __bf16* woutT = (__bf16*)(ws);
    transpose_cast<<<dim3(3072 / 32, 1024 / 32), dim3(32, 8), 0, stream>>>(Wqkv, wqkvT, 1024, 3072);
    gemm_bt<1, 1, 1, 0, 3><<<dim3(768), dim3(256), 0, stream>>>(
        (const void*)x, wqkvT, bqkv, (void*)qkvb, 4096, 3072, 1024);
    attn_fused<<<dim3(512), dim3(512), 0, stream>>>(qkvb, attnb);
    transpose_cast<<<dim3(1024 / 32, 1024 / 32), dim3(32, 8), 0, stream>>>(Wout, woutT, 1024, 1024);
    gemm_bt<0, 0, 0, 1, 2><<<dim3(512), dim3(256), 0, stream>>>(
        (const void*)attnb, woutT, bout, (void*)out, 4096, 1024, 1024);
  }
}